// Round 5
// baseline (237.639 us; speedup 1.0000x reference)
//
#include <hip/hip_runtime.h>

#define FDIM 128

typedef __attribute__((ext_vector_type(4))) float f32x4;
typedef __attribute__((ext_vector_type(8))) short s16x8;
typedef __attribute__((ext_vector_type(4))) short s16x4;

__device__ inline unsigned short f2bf(float f) {      // RNE f32->bf16
    unsigned u = __builtin_bit_cast(unsigned, f);
    u += 0x7FFFu + ((u >> 16) & 1u);
    return (unsigned short)(u >> 16);
}
__device__ inline float bflo(unsigned u) { return __builtin_bit_cast(float, u << 16); }
__device__ inline float bfhi(unsigned u) { return __builtin_bit_cast(float, u & 0xFFFF0000u); }

// ======================= CSR build (R4-proven) =======================
__global__ void hist_kernel(const int* __restrict__ dst, int* __restrict__ deg, int E) {
    int e = blockIdx.x * blockDim.x + threadIdx.x;
    if (e < E) atomicAdd(&deg[dst[e]], 1);
}

__global__ void scan1_kernel(const int* __restrict__ deg, int* __restrict__ rp,
                             int* __restrict__ bsum, int N) {
    __shared__ int s[256];
    int i = blockIdx.x * 256 + threadIdx.x;
    int v = (i < N) ? deg[i] : 0;
    s[threadIdx.x] = v;
    __syncthreads();
    for (int off = 1; off < 256; off <<= 1) {
        int t = (threadIdx.x >= off) ? s[threadIdx.x - off] : 0;
        __syncthreads();
        s[threadIdx.x] += t;
        __syncthreads();
    }
    if (i < N) rp[i] = s[threadIdx.x] - v;
    if (threadIdx.x == 255) bsum[blockIdx.x] = s[255];
}

__global__ void scan2_kernel(int* __restrict__ bsum, int nb) {
    __shared__ int s[256];
    int v = (threadIdx.x < (unsigned)nb) ? bsum[threadIdx.x] : 0;
    s[threadIdx.x] = v;
    __syncthreads();
    for (int off = 1; off < 256; off <<= 1) {
        int t = (threadIdx.x >= off) ? s[threadIdx.x - off] : 0;
        __syncthreads();
        s[threadIdx.x] += t;
        __syncthreads();
    }
    if (threadIdx.x < (unsigned)nb) bsum[threadIdx.x] = s[threadIdx.x] - v;
}

__global__ void scan3_kernel(int* __restrict__ rp, const int* __restrict__ bsum,
                             int* __restrict__ cursor, int N, int E) {
    int i = blockIdx.x * 256 + threadIdx.x;
    if (i < N) {
        int v = rp[i] + bsum[blockIdx.x];
        rp[i] = v;
        cursor[i] = v;
    } else if (i == N) {
        rp[N] = E;
    }
}

__global__ void fill_kernel(const int* __restrict__ src, const int* __restrict__ dst,
                            int* __restrict__ cursor, int* __restrict__ eid, int E) {
    int e = blockIdx.x * blockDim.x + threadIdx.x;
    if (e < E) {
        int p = atomicAdd(&cursor[dst[e]], 1);
        eid[p] = src[e];
    }
}

// ======================= bf16 prep (R4-proven) =======================
__global__ void prep_x_kernel(const float* __restrict__ x, short* __restrict__ xb, int n4) {
    int i = blockIdx.x * blockDim.x + threadIdx.x;
    if (i < n4) {
        float4 v = reinterpret_cast<const float4*>(x)[i];
        s16x4 o;
        o[0] = (short)f2bf(v.x); o[1] = (short)f2bf(v.y);
        o[2] = (short)f2bf(v.z); o[3] = (short)f2bf(v.w);
        reinterpret_cast<s16x4*>(xb)[i] = o;
    }
}

__global__ void prep_w_kernel(const float* __restrict__ Wl0, const float* __restrict__ Wr0,
                              const float* __restrict__ Wl1, const float* __restrict__ Wr1,
                              short* __restrict__ Wt0, short* __restrict__ Wt1) {
    int g = blockIdx.x * blockDim.x + threadIdx.x;   // [0, 65536)
    int n = g & 127;
    int k = (g >> 7) & 255;
    int layer = g >> 15;
    const float* Wl = layer ? Wl1 : Wl0;
    const float* Wr = layer ? Wr1 : Wr0;
    short* Wt = layer ? Wt1 : Wt0;
    float v = (k < 128) ? Wl[k * 128 + n] : Wr[(k - 128) * 128 + n];
    Wt[n * 256 + k] = (short)f2bf(v);
}

// ============== FUSED: mean-gather + [mean|x] @ [Wl;Wr] + b ==============
// Block: 64 rows x 128 cols, 4 waves. A-tile [64][256] bf16 in LDS, XOR-swizzled:
//   k<128  = gathered neighbor mean (computed in-kernel, fp32 accum)
//   k>=128 = self row of X
// No aliasing: output buffer is always distinct from X.
template <bool RELU, bool OUTF32>
__global__ __launch_bounds__(256, 3)
void fused_kernel(const short* __restrict__ X, const int* __restrict__ rp,
                  const int* __restrict__ eid, const short* __restrict__ Wt,
                  const float* __restrict__ bias, float* outf, short* outb, int n) {
    __shared__ short A_lds[64 * 256];   // 32 KB
    const int tid = threadIdx.x;
    const int w = tid >> 6, l = tid & 63;
    const int row0 = blockIdx.x * 64;

    // Phase 1a: stage self rows into the k>=128 half. 64 rows x 16 chunks(16B) = 1024.
#pragma unroll
    for (int i = 0; i < 4; ++i) {
        int c = tid + 256 * i;          // [0, 1024)
        int r = c >> 4;
        int ck = c & 15;
        int row = row0 + r;
        s16x8 v;
        if (row < n) {
            v = *reinterpret_cast<const s16x8*>(X + (size_t)row * FDIM + ck * 8);
        } else {
#pragma unroll
            for (int j = 0; j < 8; ++j) v[j] = 0;
        }
        int byte = r * 512 + ((256 + ck * 16) ^ ((r & 7) << 4));
        *reinterpret_cast<s16x8*>(reinterpret_cast<char*>(A_lds) + byte) = v;
    }

    // Phase 1b: gather means into the k<128 half. Wave w owns rows 16w..16w+15.
    // Lane l accumulates cols {2l,2l+1}; unroll 8 keeps 8x256B row-reads in flight.
    for (int rr = 0; rr < 16; ++rr) {
        int r = 16 * w + rr;
        int row = row0 + r;
        float ax = 0.f, ay = 0.f;
        int beg = 0, end = 0;
        if (row < n) { beg = rp[row]; end = rp[row + 1]; }
        int k = beg;
        for (; k + 8 <= end; k += 8) {
            unsigned u[8];
#pragma unroll
            for (int q = 0; q < 8; ++q) {
                int s = eid[k + q];
                u[q] = reinterpret_cast<const unsigned*>(X + (size_t)s * FDIM)[l];
            }
#pragma unroll
            for (int q = 0; q < 8; ++q) { ax += bflo(u[q]); ay += bfhi(u[q]); }
        }
        for (; k + 2 <= end; k += 2) {
            int s0 = eid[k], s1 = eid[k + 1];
            unsigned u0 = reinterpret_cast<const unsigned*>(X + (size_t)s0 * FDIM)[l];
            unsigned u1 = reinterpret_cast<const unsigned*>(X + (size_t)s1 * FDIM)[l];
            ax += bflo(u0) + bflo(u1);
            ay += bfhi(u0) + bfhi(u1);
        }
        for (; k < end; ++k) {
            int s = eid[k];
            unsigned u = reinterpret_cast<const unsigned*>(X + (size_t)s * FDIM)[l];
            ax += bflo(u);
            ay += bfhi(u);
        }
        float inv = (end > beg) ? 1.0f / (float)(end - beg) : 0.0f;
        unsigned lo = f2bf(ax * inv), hi = f2bf(ay * inv);
        int byte = r * 512 + ((4 * l) ^ ((r & 7) << 4));
        *reinterpret_cast<unsigned*>(reinterpret_cast<char*>(A_lds) + byte) = lo | (hi << 16);
    }

    // B fragments (L2-resident weights); issued before barrier, consumed after.
    s16x8 bfr[8][2];
    {
        const short* wb = Wt + ((32 * w + (l & 15)) * 256 + 8 * (l >> 4));
#pragma unroll
        for (int kc = 0; kc < 8; ++kc)
#pragma unroll
            for (int cf = 0; cf < 2; ++cf)
                bfr[kc][cf] = *reinterpret_cast<const s16x8*>(wb + cf * 16 * 256 + kc * 32);
    }

    __syncthreads();

    f32x4 acc[4][2];
    {
        float b0 = bias[32 * w + (l & 15)];
        float b1 = bias[32 * w + 16 + (l & 15)];
#pragma unroll
        for (int rf = 0; rf < 4; ++rf)
#pragma unroll
            for (int i = 0; i < 4; ++i) { acc[rf][0][i] = b0; acc[rf][1][i] = b1; }
    }

    const int arow = l & 15;
    const int aq16 = 16 * (l >> 4);
#pragma unroll
    for (int kc = 0; kc < 8; ++kc) {
        s16x8 afr[4];
#pragma unroll
        for (int rf = 0; rf < 4; ++rf) {
            int r = 16 * rf + arow;
            int kbyte = 64 * kc + aq16;
            int byte = r * 512 + (kbyte ^ ((r & 7) << 4));
            afr[rf] = *reinterpret_cast<const s16x8*>(reinterpret_cast<const char*>(A_lds) + byte);
        }
#pragma unroll
        for (int rf = 0; rf < 4; ++rf)
#pragma unroll
            for (int cf = 0; cf < 2; ++cf)
                acc[rf][cf] = __builtin_amdgcn_mfma_f32_16x16x32_bf16(afr[rf], bfr[kc][cf], acc[rf][cf], 0, 0, 0);
    }

    // Epilogue: D col = lane&15, row = 4*(lane>>4)+reg (R4-verified).
    const int ocol = 32 * w + (l & 15);
    const int orow = 4 * (l >> 4);
#pragma unroll
    for (int rf = 0; rf < 4; ++rf)
#pragma unroll
        for (int cf = 0; cf < 2; ++cf)
#pragma unroll
            for (int i = 0; i < 4; ++i) {
                int row = row0 + 16 * rf + orow + i;
                if (row < n) {
                    float v = acc[rf][cf][i];
                    if (RELU) v = fmaxf(v, 0.0f);
                    if (OUTF32) outf[(size_t)row * FDIM + ocol + 16 * cf] = v;
                    else        outb[(size_t)row * FDIM + ocol + 16 * cf] = (short)f2bf(v);
                }
            }
}

// ===================== fallback: atomic scatter path (R2, proven) =====================
__global__ void degree_kernel(const int* __restrict__ dst, float* __restrict__ cnt, int E) {
    int e = blockIdx.x * blockDim.x + threadIdx.x;
    if (e < E) atomicAdd(&cnt[dst[e]], 1.0f);
}

__global__ void scatter_kernel(const float* __restrict__ x, const int* __restrict__ src,
                               const int* __restrict__ dst, float* __restrict__ msg, int E) {
    int gt = blockIdx.x * blockDim.x + threadIdx.x;
    int e = gt >> 6;
    int lane = gt & 63;
    if (e >= E) return;
    int s = src[e];
    int d = dst[e];
    float2 v = reinterpret_cast<const float2*>(x + (size_t)s * FDIM)[lane];
    float* md = msg + (size_t)d * FDIM + 2 * lane;
    atomicAdd(md, v.x);
    atomicAdd(md + 1, v.y);
}

template <bool RELU>
__global__ void gemm_kernel(const float* agg, const float* cnt,
                            const float* __restrict__ xin, const float* __restrict__ Wl,
                            const float* __restrict__ Wr, const float* __restrict__ bias,
                            float* out, int n) {
    const int ROWS = 16;
    __shared__ float m_s[ROWS][FDIM];
    __shared__ float x_s[ROWS][FDIM];
    int tid = threadIdx.x;
    int row0 = blockIdx.x * ROWS;
#pragma unroll
    for (int i = 0; i < 2; ++i) {
        int idx4 = tid + i * 256;
        int r = idx4 >> 5;
        int c4 = idx4 & 31;
        int row = row0 + r;
        if (row < n) {
            float inv = cnt ? 1.0f / fmaxf(cnt[row], 1.0f) : 1.0f;
            float4 mv = reinterpret_cast<const float4*>(agg + (size_t)row * FDIM)[c4];
            float4 xv = reinterpret_cast<const float4*>(xin + (size_t)row * FDIM)[c4];
            float* mp = &m_s[r][c4 * 4];
            mp[0] = mv.x * inv; mp[1] = mv.y * inv; mp[2] = mv.z * inv; mp[3] = mv.w * inv;
            float* xp = &x_s[r][c4 * 4];
            xp[0] = xv.x; xp[1] = xv.y; xp[2] = xv.z; xp[3] = xv.w;
        }
    }
    __syncthreads();
    int j = tid & 127;
    int rh = tid >> 7;
    float acc[8];
    float bj = bias[j];
#pragma unroll
    for (int r = 0; r < 8; ++r) acc[r] = bj;
#pragma unroll 4
    for (int k = 0; k < FDIM; ++k) {
        float wl = Wl[k * FDIM + j];
        float wr = Wr[k * FDIM + j];
#pragma unroll
        for (int r = 0; r < 8; ++r)
            acc[r] += m_s[rh * 8 + r][k] * wl + x_s[rh * 8 + r][k] * wr;
    }
#pragma unroll
    for (int r = 0; r < 8; ++r) {
        int row = row0 + rh * 8 + r;
        if (row < n) {
            float v = acc[r];
            if (RELU) v = fmaxf(v, 0.0f);
            out[(size_t)row * FDIM + j] = v;
        }
    }
}

extern "C" void kernel_launch(void* const* d_in, const int* in_sizes, int n_in,
                              void* d_out, int out_size, void* d_ws, size_t ws_size,
                              hipStream_t stream) {
    const float* x   = (const float*)d_in[0];
    const int*   ei  = (const int*)d_in[1];
    const float* Wl0 = (const float*)d_in[2];
    const float* Wr0 = (const float*)d_in[3];
    const float* b0  = (const float*)d_in[4];
    const float* Wl1 = (const float*)d_in[5];
    const float* Wr1 = (const float*)d_in[6];
    const float* b1  = (const float*)d_in[7];

    int N = in_sizes[0] / FDIM;   // 50000
    int E = in_sizes[1] / 2;      // 800000
    const int* src = ei;
    const int* dst = ei + E;

    size_t featBytes  = (size_t)N * FDIM * sizeof(float);   // 25.6 MB
    size_t featBytesB = (size_t)N * FDIM * sizeof(short);   // 12.8 MB
    int edgeBlocks = (E + 255) / 256;
    int nb = (N + 255) / 256;

    // workspace layout (same 30,056,448 B footprint as R4's proven-fitting need)
    const size_t o_deg  = 0;                    // N ints
    const size_t o_rp   = 0x40000;              // N+1 ints
    const size_t o_cur  = 0x80000;              // N ints
    const size_t o_bsum = 0xC0000;              // nb ints
    const size_t o_wt0  = 0xD0000;              // 64 KB
    const size_t o_wt1  = 0xE0000;              // 64 KB
    const size_t o_eid  = 0x100000;             // E ints
    const size_t o_xb   = 0x440000;             // N*128 bf16 (x)
    const size_t o_hb   = o_xb + featBytesB;    // N*128 bf16 (h)
    const size_t need   = o_hb + featBytesB;

    if (ws_size >= need) {
        int*   deg    = (int*)((char*)d_ws + o_deg);
        int*   rp     = (int*)((char*)d_ws + o_rp);
        int*   cursor = (int*)((char*)d_ws + o_cur);
        int*   bsum   = (int*)((char*)d_ws + o_bsum);
        short* Wt0    = (short*)((char*)d_ws + o_wt0);
        short* Wt1    = (short*)((char*)d_ws + o_wt1);
        int*   eid    = (int*)((char*)d_ws + o_eid);
        short* xb     = (short*)((char*)d_ws + o_xb);
        short* hb     = (short*)((char*)d_ws + o_hb);
        float* outF   = (float*)d_out;

        // CSR build
        hipMemsetAsync(deg, 0, (size_t)N * sizeof(int), stream);
        hist_kernel<<<edgeBlocks, 256, 0, stream>>>(dst, deg, E);
        scan1_kernel<<<nb, 256, 0, stream>>>(deg, rp, bsum, N);
        scan2_kernel<<<1, 256, 0, stream>>>(bsum, nb);
        scan3_kernel<<<(N + 256) / 256, 256, 0, stream>>>(rp, bsum, cursor, N, E);
        fill_kernel<<<edgeBlocks, 256, 0, stream>>>(src, dst, cursor, eid, E);

        // bf16 prep
        prep_w_kernel<<<256, 256, 0, stream>>>(Wl0, Wr0, Wl1, Wr1, Wt0, Wt1);
        prep_x_kernel<<<(N * FDIM / 4 + 255) / 256, 256, 0, stream>>>(x, xb, N * FDIM / 4);

        int fusedBlocks = (N + 63) / 64;
        // layer 0: h = relu([mean(x)|x] @ Wcat0 + b0)   (xb -> hb, no aliasing)
        fused_kernel<true, false><<<fusedBlocks, 256, 0, stream>>>(xb, rp, eid, Wt0, b0, nullptr, hb, N);
        // layer 1: out = [mean(h)|h] @ Wcat1 + b1       (hb -> d_out f32)
        fused_kernel<false, true><<<fusedBlocks, 256, 0, stream>>>(hb, rp, eid, Wt1, b1, outF, nullptr, N);
    } else {
        // fallback: proven atomic path
        float* cnt = (float*)d_ws;
        float* h   = (float*)((char*)d_ws + (1 << 18));
        float* msg = (float*)d_out;
        int gemmBlocks = (N + 15) / 16;

        hipMemsetAsync(cnt, 0, (size_t)N * sizeof(float), stream);
        degree_kernel<<<edgeBlocks, 256, 0, stream>>>(dst, cnt, E);

        hipMemsetAsync(msg, 0, featBytes, stream);
        scatter_kernel<<<(E * 64 + 255) / 256, 256, 0, stream>>>(x, src, dst, msg, E);
        gemm_kernel<true><<<gemmBlocks, 256, 0, stream>>>(msg, cnt, x, Wl0, Wr0, b0, h, N);

        hipMemsetAsync(msg, 0, featBytes, stream);
        scatter_kernel<<<(E * 64 + 255) / 256, 256, 0, stream>>>(h, src, dst, msg, E);
        gemm_kernel<false><<<gemmBlocks, 256, 0, stream>>>(msg, cnt, h, Wl1, Wr1, b1, msg, N);
    }
}